// Round 22
// baseline (246.852 us; speedup 1.0000x reference)
//
#include <hip/hip_runtime.h>
#include <hip/hip_fp16.h>

#define N_NODES 100000
#define N_EDGES 1600000
#define NFEAT 128
#define NHID 64
#define NCLASS 40
#define SCAN_B 256
#define NTOT (N_NODES + 1)              // scan over N+1 -> offs[N] = padded total
#define PEMAX (N_EDGES + 16 * N_NODES)  // padded edge capacity (3.2M)

// CSR-build tiling: 13 bin-groups x 8192 bins; 32 edge chunks.
#define BPG 8192
#define NGROUPS 13
#define NCHUNKS 32
#define CHUNK_E (N_EDGES / NCHUNKS)   // 50000
#define HBINS (NGROUPS * BPG)         // 106496

// MFMA tiling: 64 rows/block, 4 waves x 16 rows, fp16 inputs, fp32 acc.
#define MROWS 64

typedef __attribute__((ext_vector_type(8))) _Float16 half8;
typedef __attribute__((ext_vector_type(4))) float f32x4;

// ---------------- src histogram (32 KiB LDS) ----------------
__global__ __launch_bounds__(256) void hist_src_kernel(const int* __restrict__ src,
                                                       int* __restrict__ deg_src) {
    __shared__ int hs[BPG];
    int g = blockIdx.x, c = blockIdx.y;
    int lo = g * BPG;
    for (int i = threadIdx.x; i < BPG; i += 256) hs[i] = 0;
    __syncthreads();
    const int4* s4 = (const int4*)(src + (size_t)c * CHUNK_E);
    int n4 = CHUNK_E / 4;
    for (int i = threadIdx.x; i < n4; i += 256) {
        int4 s = s4[i];
        if ((unsigned)(s.x - lo) < BPG) atomicAdd(&hs[s.x - lo], 1);
        if ((unsigned)(s.y - lo) < BPG) atomicAdd(&hs[s.y - lo], 1);
        if ((unsigned)(s.z - lo) < BPG) atomicAdd(&hs[s.z - lo], 1);
        if ((unsigned)(s.w - lo) < BPG) atomicAdd(&hs[s.w - lo], 1);
    }
    __syncthreads();
    for (int i = threadIdx.x; i < BPG; i += 256) {
        int v = hs[i];
        if (v) atomicAdd(&deg_src[lo + i], v);
    }
}

// ---------------- dst histogram + per-edge rank (32 KiB LDS) ----------------
__global__ __launch_bounds__(256) void hist_dst_kernel(const int* __restrict__ dst,
                                                       int* __restrict__ hc,
                                                       int* __restrict__ rank) {
    __shared__ int hd[BPG];
    int g = blockIdx.x, c = blockIdx.y;
    int lo = g * BPG;
    for (int i = threadIdx.x; i < BPG; i += 256) hd[i] = 0;
    __syncthreads();
    const int4* d4 = (const int4*)(dst + (size_t)c * CHUNK_E);
    int n4 = CHUNK_E / 4;
    for (int i = threadIdx.x; i < n4; i += 256) {
        int4 d = d4[i];
        int eb = c * CHUNK_E + 4 * i;
        if ((unsigned)(d.x - lo) < BPG) rank[eb + 0] = atomicAdd(&hd[d.x - lo], 1);
        if ((unsigned)(d.y - lo) < BPG) rank[eb + 1] = atomicAdd(&hd[d.y - lo], 1);
        if ((unsigned)(d.z - lo) < BPG) rank[eb + 2] = atomicAdd(&hd[d.z - lo], 1);
        if ((unsigned)(d.w - lo) < BPG) rank[eb + 3] = atomicAdd(&hd[d.w - lo], 1);
    }
    __syncthreads();
    for (int i = threadIdx.x; i < BPG; i += 256)
        hc[(size_t)c * HBINS + lo + i] = hd[i];
}

__global__ void dinv_kernel(const int* __restrict__ deg, float* __restrict__ dinv) {
    int i = blockIdx.x * blockDim.x + threadIdx.x;
    if (i < N_NODES) dinv[i] = rsqrtf((float)(deg[i] + 1));  // +1 = self loop
}

// pcnt[b] = padded (mult of 16) in-degree; pcnt[N_NODES] = 0 (scan sentinel)
__global__ void colsum_kernel(const int* __restrict__ hc, int* __restrict__ pcnt) {
    int b = blockIdx.x * 256 + threadIdx.x;
    if (b >= NTOT) return;
    if (b == N_NODES) { pcnt[b] = 0; return; }
    int s = 0;
    #pragma unroll 8
    for (int c = 0; c < NCHUNKS; ++c) s += hc[(size_t)c * HBINS + b];
    pcnt[b] = (s + 15) & ~15;
}

// ---------------- 3-kernel exclusive scan over pcnt (NTOT elements) ----------------
__global__ void scan1_kernel(const int* __restrict__ cnt, int* __restrict__ partial,
                             int* __restrict__ bsums) {
    __shared__ int tmp[SCAN_B];
    int gid = blockIdx.x * SCAN_B + threadIdx.x;
    int v = (gid < NTOT) ? cnt[gid] : 0;
    tmp[threadIdx.x] = v;
    __syncthreads();
    for (int off = 1; off < SCAN_B; off <<= 1) {
        int t = (threadIdx.x >= off) ? tmp[threadIdx.x - off] : 0;
        __syncthreads();
        tmp[threadIdx.x] += t;
        __syncthreads();
    }
    if (gid < NTOT) partial[gid] = tmp[threadIdx.x] - v;
    if (threadIdx.x == SCAN_B - 1) bsums[blockIdx.x] = tmp[threadIdx.x];
}

__global__ void scan2_kernel(int* __restrict__ bsums, int nb) {
    __shared__ int tmp[512];
    int v = (threadIdx.x < nb) ? bsums[threadIdx.x] : 0;
    tmp[threadIdx.x] = v;
    __syncthreads();
    for (int off = 1; off < 512; off <<= 1) {
        int t = (threadIdx.x >= off) ? tmp[threadIdx.x - off] : 0;
        __syncthreads();
        tmp[threadIdx.x] += t;
        __syncthreads();
    }
    if (threadIdx.x < nb) bsums[threadIdx.x] = tmp[threadIdx.x] - v;
}

__global__ void scan3_kernel(const int* __restrict__ partial, const int* __restrict__ bsums,
                             int* __restrict__ offs) {
    int gid = blockIdx.x * 256 + threadIdx.x;
    if (gid < NTOT) offs[gid] = partial[gid] + bsums[gid >> 8];
}

// base[c][b] = offs[b] + sum_{c'<c} hc[c'][b]   (real edges pack at bucket front)
__global__ void colbase_kernel(const int* __restrict__ hc, const int* __restrict__ offs,
                               int* __restrict__ base) {
    int b = blockIdx.x * 256 + threadIdx.x;
    if (b >= N_NODES) return;
    int r = offs[b];
    #pragma unroll 8
    for (int c = 0; c < NCHUNKS; ++c) {
        base[(size_t)c * HBINS + b] = r;
        r += hc[(size_t)c * HBINS + b];
    }
}

// ---------------- fill CSR: 4 edges/thread (vectorized); pad slots stay 0 from memset ----------------
__global__ __launch_bounds__(256) void fill4_kernel(const int* __restrict__ src,
                                                    const int* __restrict__ dst,
                                                    const float* __restrict__ dinv,
                                                    const int* __restrict__ base,
                                                    const int* __restrict__ rank,
                                                    int2* __restrict__ edges) {
    int q = blockIdx.x * 256 + threadIdx.x;      // quad index
    if (q >= N_EDGES / 4) return;
    int4 s = ((const int4*)src)[q];
    int4 d = ((const int4*)dst)[q];
    int4 r = ((const int4*)rank)[q];
    int c = (4 * q) / CHUNK_E;                   // CHUNK_E % 4 == 0: no chunk crossing
    const int* bc = base + (size_t)c * HBINS;
    edges[bc[d.x] + r.x] = make_int2(s.x, __float_as_int(dinv[s.x] * dinv[d.x]));
    edges[bc[d.y] + r.y] = make_int2(s.y, __float_as_int(dinv[s.y] * dinv[d.y]));
    edges[bc[d.z] + r.z] = make_int2(s.z, __float_as_int(dinv[s.z] * dinv[d.z]));
    edges[bc[d.w] + r.w] = make_int2(s.w, __float_as_int(dinv[s.w] * dinv[d.w]));
}

// ---------------- layer 1 GEMM via MFMA: h = fp16(x @ W1^T + b1) ----------------
__global__ __launch_bounds__(256) void gemm1_kernel(const float* __restrict__ x,
                                                    const float* __restrict__ W1,
                                                    const float* __restrict__ b1,
                                                    __half* __restrict__ h) {
    __shared__ _Float16 xh[MROWS * NFEAT];   // 16 KiB, swizzled
    __shared__ _Float16 wh[NHID * NFEAT];    // 16 KiB, swizzled
    int tid = threadIdx.x;
    int row0 = blockIdx.x * MROWS;

    #pragma unroll 4
    for (int i = 0; i < 16; ++i) {
        int j2 = tid + 256 * i;          // half2 index
        int row = j2 >> 6;               // 64 half2 per row
        int c2  = j2 & 63;
        float2 f = *(const float2*)(W1 + (size_t)j2 * 2);
        int byte = (row * 256 + c2 * 4) ^ ((row & 7) << 4);
        *(__half2*)((char*)wh + byte) = __floats2half2_rn(f.x, f.y);
    }
    #pragma unroll 4
    for (int i = 0; i < 16; ++i) {
        int j2 = tid + 256 * i;
        int row = j2 >> 6;
        int c2  = j2 & 63;
        int grow = row0 + row;
        float2 f = make_float2(0.f, 0.f);
        if (grow < N_NODES) f = *(const float2*)(x + (size_t)grow * NFEAT + c2 * 2);
        int byte = (row * 256 + c2 * 4) ^ ((row & 7) << 4);
        *(__half2*)((char*)xh + byte) = __floats2half2_rn(f.x, f.y);
    }
    __syncthreads();

    int l  = tid & 63;
    int w  = tid >> 6;
    int lm = l & 15;
    int lk = l >> 4;

    half8 a[4];
    #pragma unroll
    for (int ks = 0; ks < 4; ++ks) {
        int row = 16 * w + lm;
        int kb = 32 * ks + 8 * lk;
        int byte = (row * 256 + kb * 2) ^ ((row & 7) << 4);
        a[ks] = *(const half8*)((const char*)xh + byte);
    }

    f32x4 acc[4];
    #pragma unroll
    for (int ct = 0; ct < 4; ++ct) acc[ct] = (f32x4)(0.f);

    #pragma unroll
    for (int ct = 0; ct < 4; ++ct) {
        #pragma unroll
        for (int ks = 0; ks < 4; ++ks) {
            int col = 16 * ct + lm;
            int kb = 32 * ks + 8 * lk;
            int byte = (col * 256 + kb * 2) ^ ((col & 7) << 4);
            half8 b = *(const half8*)((const char*)wh + byte);
            acc[ct] = __builtin_amdgcn_mfma_f32_16x16x32_f16(a[ks], b, acc[ct], 0, 0, 0);
        }
    }

    #pragma unroll
    for (int ct = 0; ct < 4; ++ct) {
        int col = 16 * ct + lm;
        float bb = b1[col];
        #pragma unroll
        for (int r = 0; r < 4; ++r) {
            int row = row0 + 16 * w + lk * 4 + r;
            if (row < N_NODES)
                h[(size_t)row * NHID + col] = __float2half(acc[ct][r] + bb);
        }
    }
}

// ---------------- pull-aggregation layer 1 (tail-free padded buckets, int4 edge loads) ----------------
__global__ __launch_bounds__(256) void agg1_kernel(const int* __restrict__ offs,
                                                   const float* __restrict__ dinv,
                                                   const int2* __restrict__ edges,
                                                   const __half* __restrict__ h,
                                                   __half* __restrict__ z) {
    int wid = (blockIdx.x * 256 + threadIdx.x) >> 6;
    if (wid >= N_NODES) return;
    int lane = threadIdx.x & 63;
    int hw = lane >> 5;
    int fl = lane & 31;
    int start = offs[wid];
    int myn = (offs[wid + 1] - start) >> 1;   // multiple of 8
    const int4* eb4 = (const int4*)(edges + start + hw * myn);  // 16B-aligned (myn mult 8)
    float ax = 0.f, ay = 0.f;
    int n4 = myn >> 1;                        // int4 count, multiple of 4
    for (int j = 0; j < n4; j += 4) {
        int4 p0 = eb4[j], p1 = eb4[j + 1], p2 = eb4[j + 2], p3 = eb4[j + 3];
        float2 f0 = __half22float2(*(const __half2*)(h + ((size_t)p0.x << 6) + 2 * fl));
        float2 f1 = __half22float2(*(const __half2*)(h + ((size_t)p0.z << 6) + 2 * fl));
        float2 f2 = __half22float2(*(const __half2*)(h + ((size_t)p1.x << 6) + 2 * fl));
        float2 f3 = __half22float2(*(const __half2*)(h + ((size_t)p1.z << 6) + 2 * fl));
        float2 f4 = __half22float2(*(const __half2*)(h + ((size_t)p2.x << 6) + 2 * fl));
        float2 f5 = __half22float2(*(const __half2*)(h + ((size_t)p2.z << 6) + 2 * fl));
        float2 f6 = __half22float2(*(const __half2*)(h + ((size_t)p3.x << 6) + 2 * fl));
        float2 f7 = __half22float2(*(const __half2*)(h + ((size_t)p3.z << 6) + 2 * fl));
        float w0 = __int_as_float(p0.y), w1 = __int_as_float(p0.w);
        float w2 = __int_as_float(p1.y), w3 = __int_as_float(p1.w);
        float w4 = __int_as_float(p2.y), w5 = __int_as_float(p2.w);
        float w6 = __int_as_float(p3.y), w7 = __int_as_float(p3.w);
        ax += w0 * f0.x + w1 * f1.x + w2 * f2.x + w3 * f3.x
            + w4 * f4.x + w5 * f5.x + w6 * f6.x + w7 * f7.x;
        ay += w0 * f0.y + w1 * f1.y + w2 * f2.y + w3 * f3.y
            + w4 * f4.y + w5 * f5.y + w6 * f6.y + w7 * f7.y;
    }
    ax += __shfl_xor(ax, 32);
    ay += __shfl_xor(ay, 32);
    if (hw == 0) {
        float di = dinv[wid];
        float2 f = __half22float2(*(const __half2*)(h + ((size_t)wid << 6) + 2 * fl));
        ax += di * di * f.x;
        ay += di * di * f.y;
        *(__half2*)(z + ((size_t)wid << 6) + 2 * fl) =
            __floats2half2_rn(fmaxf(ax, 0.f), fmaxf(ay, 0.f));
    }
}

// ---------------- layer 2 GEMM via MFMA: h2p = fp16(z @ W2^T + b2), padded stride 64 ----------------
__global__ __launch_bounds__(256) void gemm2_kernel(const __half* __restrict__ z,
                                                    const float* __restrict__ W2,
                                                    const float* __restrict__ b2,
                                                    __half* __restrict__ h2p) {
    __shared__ _Float16 zh[MROWS * NHID];    // 8 KiB, swizzled
    __shared__ _Float16 w2h[48 * NHID];      // 6 KiB, swizzled (cols 40-47 zero)
    __shared__ float b2l[48];
    int tid = threadIdx.x;
    int row0 = blockIdx.x * MROWS;

    if (tid < 48) b2l[tid] = (tid < NCLASS) ? b2[tid] : 0.f;
    #pragma unroll 2
    for (int i = 0; i < 8; ++i) {
        int j2 = tid + 256 * i;
        int row = j2 >> 5;               // 32 half2 per row
        int c2  = j2 & 31;
        int grow = row0 + row;
        __half2 v = __floats2half2_rn(0.f, 0.f);
        if (grow < N_NODES) v = *(const __half2*)(z + ((size_t)grow << 6) + c2 * 2);
        int byte = (row * 128 + c2 * 4) ^ ((row & 7) << 4);
        *(__half2*)((char*)zh + byte) = v;
    }
    #pragma unroll 2
    for (int i = 0; i < 6; ++i) {
        int j2 = tid + 256 * i;          // 48*32 = 1536 slots
        int col = j2 >> 5;
        int c2  = j2 & 31;
        float2 f = make_float2(0.f, 0.f);
        if (col < NCLASS) f = *(const float2*)(W2 + (size_t)col * NHID + c2 * 2);
        int byte = (col * 128 + c2 * 4) ^ ((col & 7) << 4);
        *(__half2*)((char*)w2h + byte) = __floats2half2_rn(f.x, f.y);
    }
    __syncthreads();

    int l  = tid & 63;
    int w  = tid >> 6;
    int lm = l & 15;
    int lk = l >> 4;

    half8 a[2];
    #pragma unroll
    for (int ks = 0; ks < 2; ++ks) {
        int row = 16 * w + lm;
        int kb = 32 * ks + 8 * lk;
        int byte = (row * 128 + kb * 2) ^ ((row & 7) << 4);
        a[ks] = *(const half8*)((const char*)zh + byte);
    }

    f32x4 acc[3];
    #pragma unroll
    for (int ct = 0; ct < 3; ++ct) acc[ct] = (f32x4)(0.f);

    #pragma unroll
    for (int ct = 0; ct < 3; ++ct) {
        #pragma unroll
        for (int ks = 0; ks < 2; ++ks) {
            int col = 16 * ct + lm;
            int kb = 32 * ks + 8 * lk;
            int byte = (col * 128 + kb * 2) ^ ((col & 7) << 4);
            half8 b = *(const half8*)((const char*)w2h + byte);
            acc[ct] = __builtin_amdgcn_mfma_f32_16x16x32_f16(a[ks], b, acc[ct], 0, 0, 0);
        }
    }

    #pragma unroll
    for (int ct = 0; ct < 3; ++ct) {
        int col = 16 * ct + lm;          // cols 40..47 land in h2p padding (never read)
        float bb = b2l[col];
        #pragma unroll
        for (int r = 0; r < 4; ++r) {
            int row = row0 + 16 * w + lk * 4 + r;
            if (row < N_NODES)
                h2p[((size_t)row << 6) + col] = __float2half(acc[ct][r] + bb);
        }
    }
}

// ---------------- pull-aggregation layer 2 + fused log_softmax (padded, int4 edge loads) ----------------
__global__ __launch_bounds__(256) void agg2_kernel(const int* __restrict__ offs,
                                                   const float* __restrict__ dinv,
                                                   const int2* __restrict__ edges,
                                                   const __half* __restrict__ h2p,
                                                   float* __restrict__ out) {
    int wid = (blockIdx.x * 256 + threadIdx.x) >> 6;
    if (wid >= N_NODES) return;
    int lane = threadIdx.x & 63;
    int hw = lane >> 5;
    int fl = lane & 31;
    bool act = fl < NCLASS / 2;
    int start = offs[wid];
    int myn = (offs[wid + 1] - start) >> 1;   // multiple of 8
    const int4* eb4 = (const int4*)(edges + start + hw * myn);
    float ax = 0.f, ay = 0.f;
    int n4 = myn >> 1;
    if (act) {
        for (int j = 0; j < n4; j += 4) {
            int4 p0 = eb4[j], p1 = eb4[j + 1], p2 = eb4[j + 2], p3 = eb4[j + 3];
            float2 f0 = __half22float2(*(const __half2*)(h2p + ((size_t)p0.x << 6) + 2 * fl));
            float2 f1 = __half22float2(*(const __half2*)(h2p + ((size_t)p0.z << 6) + 2 * fl));
            float2 f2 = __half22float2(*(const __half2*)(h2p + ((size_t)p1.x << 6) + 2 * fl));
            float2 f3 = __half22float2(*(const __half2*)(h2p + ((size_t)p1.z << 6) + 2 * fl));
            float2 f4 = __half22float2(*(const __half2*)(h2p + ((size_t)p2.x << 6) + 2 * fl));
            float2 f5 = __half22float2(*(const __half2*)(h2p + ((size_t)p2.z << 6) + 2 * fl));
            float2 f6 = __half22float2(*(const __half2*)(h2p + ((size_t)p3.x << 6) + 2 * fl));
            float2 f7 = __half22float2(*(const __half2*)(h2p + ((size_t)p3.z << 6) + 2 * fl));
            float w0 = __int_as_float(p0.y), w1 = __int_as_float(p0.w);
            float w2 = __int_as_float(p1.y), w3 = __int_as_float(p1.w);
            float w4 = __int_as_float(p2.y), w5 = __int_as_float(p2.w);
            float w6 = __int_as_float(p3.y), w7 = __int_as_float(p3.w);
            ax += w0 * f0.x + w1 * f1.x + w2 * f2.x + w3 * f3.x
                + w4 * f4.x + w5 * f5.x + w6 * f6.x + w7 * f7.x;
            ay += w0 * f0.y + w1 * f1.y + w2 * f2.y + w3 * f3.y
                + w4 * f4.y + w5 * f5.y + w6 * f6.y + w7 * f7.y;
        }
    }
    ax += __shfl_xor(ax, 32);
    ay += __shfl_xor(ay, 32);
    float di = dinv[wid];
    if (act) {
        float dsq = di * di;
        float2 f = __half22float2(*(const __half2*)(h2p + ((size_t)wid << 6) + 2 * fl));
        ax += dsq * f.x;
        ay += dsq * f.y;
    }
    float m = act ? fmaxf(ax, ay) : -INFINITY;
    #pragma unroll
    for (int o = 16; o > 0; o >>= 1) m = fmaxf(m, __shfl_xor(m, o));
    float s = act ? (__expf(ax - m) + __expf(ay - m)) : 0.f;
    #pragma unroll
    for (int o = 16; o > 0; o >>= 1) s += __shfl_xor(s, o);
    if (hw == 0 && act) {
        float lse = m + logf(s);
        *(float2*)(out + (size_t)wid * NCLASS + 2 * fl) = make_float2(ax - lse, ay - lse);
    }
}

extern "C" void kernel_launch(void* const* d_in, const int* in_sizes, int n_in,
                              void* d_out, int out_size, void* d_ws, size_t ws_size,
                              hipStream_t stream) {
    const float* x  = (const float*)d_in[0];
    const float* W1 = (const float*)d_in[1];
    const float* b1 = (const float*)d_in[2];
    const float* W2 = (const float*)d_in[3];
    const float* b2 = (const float*)d_in[4];
    const int*   ei = (const int*)d_in[5];
    const int* src = ei;
    const int* dst = ei + N_EDGES;
    float* out = (float*)d_out;

    char* ws = (char*)d_ws;
    int*    deg_src = (int*)ws;    ws += 400128;
    int*    pcnt    = (int*)ws;    ws += 400128;   // NTOT ints
    int*    offs    = (int*)ws;    ws += 400128;   // NTOT ints
    int*    partial = (int*)ws;    ws += 400128;   // NTOT ints
    int*    bsums   = (int*)ws;    ws += 2048;
    float*  dinv    = (float*)ws;  ws += 400128;
    int*    hc      = (int*)ws;    ws += (size_t)NCHUNKS * HBINS * sizeof(int);  // 13.6 MB
    int*    base    = (int*)ws;    ws += (size_t)NCHUNKS * HBINS * sizeof(int);  // 13.6 MB
    int*    rank    = (int*)ws;    ws += (size_t)N_EDGES * sizeof(int);          // 6.4 MB
    int2*   edges   = (int2*)ws;   ws += (size_t)PEMAX * sizeof(int2);           // 25.6 MB
    __half* h       = (__half*)ws; ws += (size_t)N_NODES * NHID * sizeof(__half);
    __half* z       = (__half*)ws; ws += (size_t)N_NODES * NHID * sizeof(__half);
    __half* h2p     = (__half*)ws; ws += (size_t)N_NODES * 64 * sizeof(__half);

    hipMemsetAsync(deg_src, 0, (size_t)N_NODES * sizeof(int), stream);
    hipMemsetAsync(edges, 0, (size_t)PEMAX * sizeof(int2), stream);  // pad slots -> w=0

    dim3 hgrid(NGROUPS, NCHUNKS);   // 13 x 32 = 416 blocks each
    hist_src_kernel<<<hgrid, 256, 0, stream>>>(src, deg_src);
    hist_dst_kernel<<<hgrid, 256, 0, stream>>>(dst, hc, rank);
    dinv_kernel<<<(N_NODES + 255) / 256, 256, 0, stream>>>(deg_src, dinv);
    colsum_kernel<<<(NTOT + 255) / 256, 256, 0, stream>>>(hc, pcnt);

    int nsb = (NTOT + SCAN_B - 1) / SCAN_B;  // 391 <= 512
    scan1_kernel<<<nsb, SCAN_B, 0, stream>>>(pcnt, partial, bsums);
    scan2_kernel<<<1, 512, 0, stream>>>(bsums, nsb);
    scan3_kernel<<<(NTOT + 255) / 256, 256, 0, stream>>>(partial, bsums, offs);
    colbase_kernel<<<(N_NODES + 255) / 256, 256, 0, stream>>>(hc, offs, base);

    fill4_kernel<<<(N_EDGES / 4 + 255) / 256, 256, 0, stream>>>(src, dst, dinv, base, rank, edges);

    gemm1_kernel<<<(N_NODES + MROWS - 1) / MROWS, 256, 0, stream>>>(x, W1, b1, h);

    int nwblk = (N_NODES * 64 + 255) / 256;  // 25000 blocks, 4 waves each
    agg1_kernel<<<nwblk, 256, 0, stream>>>(offs, dinv, edges, h, z);
    gemm2_kernel<<<(N_NODES + MROWS - 1) / MROWS, 256, 0, stream>>>(z, W2, b2, h2p);
    agg2_kernel<<<nwblk, 256, 0, stream>>>(offs, dinv, edges, h2p, out);
}

// Round 24
// 243.500 us; speedup vs baseline: 1.0138x; 1.0138x over previous
//
#include <hip/hip_runtime.h>
#include <hip/hip_fp16.h>

#define N_NODES 100000
#define N_EDGES 1600000
#define NFEAT 128
#define NHID 64
#define NCLASS 40
#define SCAN_B 256
#define NTOT (N_NODES + 1)              // scan over N+1 -> offs[N] = padded total
#define PEMAX (N_EDGES + 16 * N_NODES)  // padded edge capacity (3.2M)

// CSR-build tiling: 13 bin-groups x 8192 bins; 64 edge chunks (832 blocks -> ~3.3/CU).
#define BPG 8192
#define NGROUPS 13
#define NCHUNKS 64
#define CHUNK_E (N_EDGES / NCHUNKS)   // 25000 (divisible by 4)
#define HBINS (NGROUPS * BPG)         // 106496

// MFMA tiling: 64 rows/block, 4 waves x 16 rows, fp16 inputs, fp32 acc.
#define MROWS 64

typedef __attribute__((ext_vector_type(8))) _Float16 half8;
typedef __attribute__((ext_vector_type(4))) float f32x4;

// ---------------- src histogram (32 KiB LDS) ----------------
__global__ __launch_bounds__(256) void hist_src_kernel(const int* __restrict__ src,
                                                       int* __restrict__ deg_src) {
    __shared__ int hs[BPG];
    int g = blockIdx.x, c = blockIdx.y;
    int lo = g * BPG;
    for (int i = threadIdx.x; i < BPG; i += 256) hs[i] = 0;
    __syncthreads();
    const int4* s4 = (const int4*)(src + (size_t)c * CHUNK_E);
    int n4 = CHUNK_E / 4;
    for (int i = threadIdx.x; i < n4; i += 256) {
        int4 s = s4[i];
        if ((unsigned)(s.x - lo) < BPG) atomicAdd(&hs[s.x - lo], 1);
        if ((unsigned)(s.y - lo) < BPG) atomicAdd(&hs[s.y - lo], 1);
        if ((unsigned)(s.z - lo) < BPG) atomicAdd(&hs[s.z - lo], 1);
        if ((unsigned)(s.w - lo) < BPG) atomicAdd(&hs[s.w - lo], 1);
    }
    __syncthreads();
    for (int i = threadIdx.x; i < BPG; i += 256) {
        int v = hs[i];
        if (v) atomicAdd(&deg_src[lo + i], v);
    }
}

// ---------------- dst histogram + per-edge rank; counts stored uint16 ----------------
__global__ __launch_bounds__(256) void hist_dst_kernel(const int* __restrict__ dst,
                                                       unsigned short* __restrict__ hc16,
                                                       int* __restrict__ rank) {
    __shared__ int hd[BPG];
    int g = blockIdx.x, c = blockIdx.y;
    int lo = g * BPG;
    for (int i = threadIdx.x; i < BPG; i += 256) hd[i] = 0;
    __syncthreads();
    const int4* d4 = (const int4*)(dst + (size_t)c * CHUNK_E);
    int n4 = CHUNK_E / 4;
    for (int i = threadIdx.x; i < n4; i += 256) {
        int4 d = d4[i];
        int eb = c * CHUNK_E + 4 * i;
        if ((unsigned)(d.x - lo) < BPG) rank[eb + 0] = atomicAdd(&hd[d.x - lo], 1);
        if ((unsigned)(d.y - lo) < BPG) rank[eb + 1] = atomicAdd(&hd[d.y - lo], 1);
        if ((unsigned)(d.z - lo) < BPG) rank[eb + 2] = atomicAdd(&hd[d.z - lo], 1);
        if ((unsigned)(d.w - lo) < BPG) rank[eb + 3] = atomicAdd(&hd[d.w - lo], 1);
    }
    __syncthreads();
    for (int i = threadIdx.x; i < BPG; i += 256)
        hc16[(size_t)c * HBINS + lo + i] = (unsigned short)hd[i];
}

// ---------------- fused prep: cum-prefix, padded count, dinv ----------------
__global__ void prep_kernel(const unsigned short* __restrict__ hc16,
                            const int* __restrict__ deg_src,
                            unsigned short* __restrict__ cum16,
                            int* __restrict__ pcnt,
                            float* __restrict__ dinv) {
    int b = blockIdx.x * 256 + threadIdx.x;
    if (b >= NTOT) return;
    if (b == N_NODES) { pcnt[b] = 0; return; }
    int r = 0;
    #pragma unroll 16
    for (int c = 0; c < NCHUNKS; ++c) {
        cum16[(size_t)c * HBINS + b] = (unsigned short)r;
        r += hc16[(size_t)c * HBINS + b];
    }
    pcnt[b] = (r + 15) & ~15;
    dinv[b] = rsqrtf((float)(deg_src[b] + 1));  // +1 = self loop
}

// ---------------- 3-kernel exclusive scan over pcnt (NTOT elements) ----------------
__global__ void scan1_kernel(const int* __restrict__ cnt, int* __restrict__ partial,
                             int* __restrict__ bsums) {
    __shared__ int tmp[SCAN_B];
    int gid = blockIdx.x * SCAN_B + threadIdx.x;
    int v = (gid < NTOT) ? cnt[gid] : 0;
    tmp[threadIdx.x] = v;
    __syncthreads();
    for (int off = 1; off < SCAN_B; off <<= 1) {
        int t = (threadIdx.x >= off) ? tmp[threadIdx.x - off] : 0;
        __syncthreads();
        tmp[threadIdx.x] += t;
        __syncthreads();
    }
    if (gid < NTOT) partial[gid] = tmp[threadIdx.x] - v;
    if (threadIdx.x == SCAN_B - 1) bsums[blockIdx.x] = tmp[threadIdx.x];
}

__global__ void scan2_kernel(int* __restrict__ bsums, int nb) {
    __shared__ int tmp[512];
    int v = (threadIdx.x < nb) ? bsums[threadIdx.x] : 0;
    tmp[threadIdx.x] = v;
    __syncthreads();
    for (int off = 1; off < 512; off <<= 1) {
        int t = (threadIdx.x >= off) ? tmp[threadIdx.x - off] : 0;
        __syncthreads();
        tmp[threadIdx.x] += t;
        __syncthreads();
    }
    if (threadIdx.x < nb) bsums[threadIdx.x] = tmp[threadIdx.x] - v;
}

__global__ void scan3_kernel(const int* __restrict__ partial, const int* __restrict__ bsums,
                             int* __restrict__ offs) {
    int gid = blockIdx.x * 256 + threadIdx.x;
    if (gid < NTOT) offs[gid] = partial[gid] + bsums[gid >> 8];
}

// ---------------- fill CSR: 4 edges/thread; pad slots stay 0 from memset ----------------
__global__ __launch_bounds__(256) void fill4_kernel(const int* __restrict__ src,
                                                    const int* __restrict__ dst,
                                                    const float* __restrict__ dinv,
                                                    const int* __restrict__ offs,
                                                    const unsigned short* __restrict__ cum16,
                                                    const int* __restrict__ rank,
                                                    int2* __restrict__ edges) {
    int q = blockIdx.x * 256 + threadIdx.x;      // quad index
    if (q >= N_EDGES / 4) return;
    int4 s = ((const int4*)src)[q];
    int4 d = ((const int4*)dst)[q];
    int4 r = ((const int4*)rank)[q];
    int c = (4 * q) / CHUNK_E;                   // CHUNK_E % 4 == 0: no chunk crossing
    const unsigned short* cc = cum16 + (size_t)c * HBINS;
    edges[offs[d.x] + cc[d.x] + r.x] = make_int2(s.x, __float_as_int(dinv[s.x] * dinv[d.x]));
    edges[offs[d.y] + cc[d.y] + r.y] = make_int2(s.y, __float_as_int(dinv[s.y] * dinv[d.y]));
    edges[offs[d.z] + cc[d.z] + r.z] = make_int2(s.z, __float_as_int(dinv[s.z] * dinv[d.z]));
    edges[offs[d.w] + cc[d.w] + r.w] = make_int2(s.w, __float_as_int(dinv[s.w] * dinv[d.w]));
}

// ---------------- layer 1 GEMM via MFMA: h = fp16(x @ W1^T + b1) ----------------
__global__ __launch_bounds__(256) void gemm1_kernel(const float* __restrict__ x,
                                                    const float* __restrict__ W1,
                                                    const float* __restrict__ b1,
                                                    __half* __restrict__ h) {
    __shared__ _Float16 xh[MROWS * NFEAT];   // 16 KiB, swizzled
    __shared__ _Float16 wh[NHID * NFEAT];    // 16 KiB, swizzled
    int tid = threadIdx.x;
    int row0 = blockIdx.x * MROWS;

    #pragma unroll 4
    for (int i = 0; i < 16; ++i) {
        int j2 = tid + 256 * i;          // half2 index
        int row = j2 >> 6;               // 64 half2 per row
        int c2  = j2 & 63;
        float2 f = *(const float2*)(W1 + (size_t)j2 * 2);
        int byte = (row * 256 + c2 * 4) ^ ((row & 7) << 4);
        *(__half2*)((char*)wh + byte) = __floats2half2_rn(f.x, f.y);
    }
    #pragma unroll 4
    for (int i = 0; i < 16; ++i) {
        int j2 = tid + 256 * i;
        int row = j2 >> 6;
        int c2  = j2 & 63;
        int grow = row0 + row;
        float2 f = make_float2(0.f, 0.f);
        if (grow < N_NODES) f = *(const float2*)(x + (size_t)grow * NFEAT + c2 * 2);
        int byte = (row * 256 + c2 * 4) ^ ((row & 7) << 4);
        *(__half2*)((char*)xh + byte) = __floats2half2_rn(f.x, f.y);
    }
    __syncthreads();

    int l  = tid & 63;
    int w  = tid >> 6;
    int lm = l & 15;
    int lk = l >> 4;

    half8 a[4];
    #pragma unroll
    for (int ks = 0; ks < 4; ++ks) {
        int row = 16 * w + lm;
        int kb = 32 * ks + 8 * lk;
        int byte = (row * 256 + kb * 2) ^ ((row & 7) << 4);
        a[ks] = *(const half8*)((const char*)xh + byte);
    }

    f32x4 acc[4];
    #pragma unroll
    for (int ct = 0; ct < 4; ++ct) acc[ct] = (f32x4)(0.f);

    #pragma unroll
    for (int ct = 0; ct < 4; ++ct) {
        #pragma unroll
        for (int ks = 0; ks < 4; ++ks) {
            int col = 16 * ct + lm;
            int kb = 32 * ks + 8 * lk;
            int byte = (col * 256 + kb * 2) ^ ((col & 7) << 4);
            half8 b = *(const half8*)((const char*)wh + byte);
            acc[ct] = __builtin_amdgcn_mfma_f32_16x16x32_f16(a[ks], b, acc[ct], 0, 0, 0);
        }
    }

    #pragma unroll
    for (int ct = 0; ct < 4; ++ct) {
        int col = 16 * ct + lm;
        float bb = b1[col];
        #pragma unroll
        for (int r = 0; r < 4; ++r) {
            int row = row0 + 16 * w + lk * 4 + r;
            if (row < N_NODES)
                h[(size_t)row * NHID + col] = __float2half(acc[ct][r] + bb);
        }
    }
}

// ---------------- pull-aggregation layer 1 (tail-free padded buckets, int4 edge loads) ----------------
__global__ __launch_bounds__(256) void agg1_kernel(const int* __restrict__ offs,
                                                   const float* __restrict__ dinv,
                                                   const int2* __restrict__ edges,
                                                   const __half* __restrict__ h,
                                                   __half* __restrict__ z) {
    int wid = (blockIdx.x * 256 + threadIdx.x) >> 6;
    if (wid >= N_NODES) return;
    int lane = threadIdx.x & 63;
    int hw = lane >> 5;
    int fl = lane & 31;
    int start = offs[wid];
    int myn = (offs[wid + 1] - start) >> 1;   // multiple of 8
    const int4* eb4 = (const int4*)(edges + start + hw * myn);
    float ax = 0.f, ay = 0.f;
    int n4 = myn >> 1;                        // int4 count, multiple of 4
    for (int j = 0; j < n4; j += 4) {
        int4 p0 = eb4[j], p1 = eb4[j + 1], p2 = eb4[j + 2], p3 = eb4[j + 3];
        float2 f0 = __half22float2(*(const __half2*)(h + ((size_t)p0.x << 6) + 2 * fl));
        float2 f1 = __half22float2(*(const __half2*)(h + ((size_t)p0.z << 6) + 2 * fl));
        float2 f2 = __half22float2(*(const __half2*)(h + ((size_t)p1.x << 6) + 2 * fl));
        float2 f3 = __half22float2(*(const __half2*)(h + ((size_t)p1.z << 6) + 2 * fl));
        float2 f4 = __half22float2(*(const __half2*)(h + ((size_t)p2.x << 6) + 2 * fl));
        float2 f5 = __half22float2(*(const __half2*)(h + ((size_t)p2.z << 6) + 2 * fl));
        float2 f6 = __half22float2(*(const __half2*)(h + ((size_t)p3.x << 6) + 2 * fl));
        float2 f7 = __half22float2(*(const __half2*)(h + ((size_t)p3.z << 6) + 2 * fl));
        float w0 = __int_as_float(p0.y), w1 = __int_as_float(p0.w);
        float w2 = __int_as_float(p1.y), w3 = __int_as_float(p1.w);
        float w4 = __int_as_float(p2.y), w5 = __int_as_float(p2.w);
        float w6 = __int_as_float(p3.y), w7 = __int_as_float(p3.w);
        ax += w0 * f0.x + w1 * f1.x + w2 * f2.x + w3 * f3.x
            + w4 * f4.x + w5 * f5.x + w6 * f6.x + w7 * f7.x;
        ay += w0 * f0.y + w1 * f1.y + w2 * f2.y + w3 * f3.y
            + w4 * f4.y + w5 * f5.y + w6 * f6.y + w7 * f7.y;
    }
    ax += __shfl_xor(ax, 32);
    ay += __shfl_xor(ay, 32);
    if (hw == 0) {
        float di = dinv[wid];
        float2 f = __half22float2(*(const __half2*)(h + ((size_t)wid << 6) + 2 * fl));
        ax += di * di * f.x;
        ay += di * di * f.y;
        *(__half2*)(z + ((size_t)wid << 6) + 2 * fl) =
            __floats2half2_rn(fmaxf(ax, 0.f), fmaxf(ay, 0.f));
    }
}

// ---------------- layer 2 GEMM via MFMA: h2p = fp16(z @ W2^T + b2), padded stride 64 ----------------
__global__ __launch_bounds__(256) void gemm2_kernel(const __half* __restrict__ z,
                                                    const float* __restrict__ W2,
                                                    const float* __restrict__ b2,
                                                    __half* __restrict__ h2p) {
    __shared__ _Float16 zh[MROWS * NHID];    // 8 KiB, swizzled
    __shared__ _Float16 w2h[48 * NHID];      // 6 KiB, swizzled (cols 40-47 zero)
    __shared__ float b2l[48];
    int tid = threadIdx.x;
    int row0 = blockIdx.x * MROWS;

    if (tid < 48) b2l[tid] = (tid < NCLASS) ? b2[tid] : 0.f;
    #pragma unroll 2
    for (int i = 0; i < 8; ++i) {
        int j2 = tid + 256 * i;
        int row = j2 >> 5;               // 32 half2 per row
        int c2  = j2 & 31;
        int grow = row0 + row;
        __half2 v = __floats2half2_rn(0.f, 0.f);
        if (grow < N_NODES) v = *(const __half2*)(z + ((size_t)grow << 6) + c2 * 2);
        int byte = (row * 128 + c2 * 4) ^ ((row & 7) << 4);
        *(__half2*)((char*)zh + byte) = v;
    }
    #pragma unroll 2
    for (int i = 0; i < 6; ++i) {
        int j2 = tid + 256 * i;          // 48*32 = 1536 slots
        int col = j2 >> 5;
        int c2  = j2 & 31;
        float2 f = make_float2(0.f, 0.f);
        if (col < NCLASS) f = *(const float2*)(W2 + (size_t)col * NHID + c2 * 2);
        int byte = (col * 128 + c2 * 4) ^ ((col & 7) << 4);
        *(__half2*)((char*)w2h + byte) = __floats2half2_rn(f.x, f.y);
    }
    __syncthreads();

    int l  = tid & 63;
    int w  = tid >> 6;
    int lm = l & 15;
    int lk = l >> 4;

    half8 a[2];
    #pragma unroll
    for (int ks = 0; ks < 2; ++ks) {
        int row = 16 * w + lm;
        int kb = 32 * ks + 8 * lk;
        int byte = (row * 128 + kb * 2) ^ ((row & 7) << 4);
        a[ks] = *(const half8*)((const char*)zh + byte);
    }

    f32x4 acc[3];
    #pragma unroll
    for (int ct = 0; ct < 3; ++ct) acc[ct] = (f32x4)(0.f);

    #pragma unroll
    for (int ct = 0; ct < 3; ++ct) {
        #pragma unroll
        for (int ks = 0; ks < 2; ++ks) {
            int col = 16 * ct + lm;
            int kb = 32 * ks + 8 * lk;
            int byte = (col * 128 + kb * 2) ^ ((col & 7) << 4);
            half8 b = *(const half8*)((const char*)w2h + byte);
            acc[ct] = __builtin_amdgcn_mfma_f32_16x16x32_f16(a[ks], b, acc[ct], 0, 0, 0);
        }
    }

    #pragma unroll
    for (int ct = 0; ct < 3; ++ct) {
        int col = 16 * ct + lm;          // cols 40..47 land in h2p padding (never read)
        float bb = b2l[col];
        #pragma unroll
        for (int r = 0; r < 4; ++r) {
            int row = row0 + 16 * w + lk * 4 + r;
            if (row < N_NODES)
                h2p[((size_t)row << 6) + col] = __float2half(acc[ct][r] + bb);
        }
    }
}

// ---------------- pull-aggregation layer 2 + fused log_softmax (padded, int4 edge loads) ----------------
__global__ __launch_bounds__(256) void agg2_kernel(const int* __restrict__ offs,
                                                   const float* __restrict__ dinv,
                                                   const int2* __restrict__ edges,
                                                   const __half* __restrict__ h2p,
                                                   float* __restrict__ out) {
    int wid = (blockIdx.x * 256 + threadIdx.x) >> 6;
    if (wid >= N_NODES) return;
    int lane = threadIdx.x & 63;
    int hw = lane >> 5;
    int fl = lane & 31;
    bool act = fl < NCLASS / 2;
    int start = offs[wid];
    int myn = (offs[wid + 1] - start) >> 1;   // multiple of 8
    const int4* eb4 = (const int4*)(edges + start + hw * myn);
    float ax = 0.f, ay = 0.f;
    int n4 = myn >> 1;
    if (act) {
        for (int j = 0; j < n4; j += 4) {
            int4 p0 = eb4[j], p1 = eb4[j + 1], p2 = eb4[j + 2], p3 = eb4[j + 3];
            float2 f0 = __half22float2(*(const __half2*)(h2p + ((size_t)p0.x << 6) + 2 * fl));
            float2 f1 = __half22float2(*(const __half2*)(h2p + ((size_t)p0.z << 6) + 2 * fl));
            float2 f2 = __half22float2(*(const __half2*)(h2p + ((size_t)p1.x << 6) + 2 * fl));
            float2 f3 = __half22float2(*(const __half2*)(h2p + ((size_t)p1.z << 6) + 2 * fl));
            float2 f4 = __half22float2(*(const __half2*)(h2p + ((size_t)p2.x << 6) + 2 * fl));
            float2 f5 = __half22float2(*(const __half2*)(h2p + ((size_t)p2.z << 6) + 2 * fl));
            float2 f6 = __half22float2(*(const __half2*)(h2p + ((size_t)p3.x << 6) + 2 * fl));
            float2 f7 = __half22float2(*(const __half2*)(h2p + ((size_t)p3.z << 6) + 2 * fl));
            float w0 = __int_as_float(p0.y), w1 = __int_as_float(p0.w);
            float w2 = __int_as_float(p1.y), w3 = __int_as_float(p1.w);
            float w4 = __int_as_float(p2.y), w5 = __int_as_float(p2.w);
            float w6 = __int_as_float(p3.y), w7 = __int_as_float(p3.w);
            ax += w0 * f0.x + w1 * f1.x + w2 * f2.x + w3 * f3.x
                + w4 * f4.x + w5 * f5.x + w6 * f6.x + w7 * f7.x;
            ay += w0 * f0.y + w1 * f1.y + w2 * f2.y + w3 * f3.y
                + w4 * f4.y + w5 * f5.y + w6 * f6.y + w7 * f7.y;
        }
    }
    ax += __shfl_xor(ax, 32);
    ay += __shfl_xor(ay, 32);
    float di = dinv[wid];
    if (act) {
        float dsq = di * di;
        float2 f = __half22float2(*(const __half2*)(h2p + ((size_t)wid << 6) + 2 * fl));
        ax += dsq * f.x;
        ay += dsq * f.y;
    }
    float m = act ? fmaxf(ax, ay) : -INFINITY;
    #pragma unroll
    for (int o = 16; o > 0; o >>= 1) m = fmaxf(m, __shfl_xor(m, o));
    float s = act ? (__expf(ax - m) + __expf(ay - m)) : 0.f;
    #pragma unroll
    for (int o = 16; o > 0; o >>= 1) s += __shfl_xor(s, o);
    if (hw == 0 && act) {
        float lse = m + logf(s);
        *(float2*)(out + (size_t)wid * NCLASS + 2 * fl) = make_float2(ax - lse, ay - lse);
    }
}

extern "C" void kernel_launch(void* const* d_in, const int* in_sizes, int n_in,
                              void* d_out, int out_size, void* d_ws, size_t ws_size,
                              hipStream_t stream) {
    const float* x  = (const float*)d_in[0];
    const float* W1 = (const float*)d_in[1];
    const float* b1 = (const float*)d_in[2];
    const float* W2 = (const float*)d_in[3];
    const float* b2 = (const float*)d_in[4];
    const int*   ei = (const int*)d_in[5];
    const int* src = ei;
    const int* dst = ei + N_EDGES;
    float* out = (float*)d_out;

    char* ws = (char*)d_ws;
    int*    deg_src = (int*)ws;    ws += 400128;
    int*    pcnt    = (int*)ws;    ws += 400128;   // NTOT ints
    int*    offs    = (int*)ws;    ws += 400128;   // NTOT ints
    int*    partial = (int*)ws;    ws += 400128;   // NTOT ints
    int*    bsums   = (int*)ws;    ws += 2048;
    float*  dinv    = (float*)ws;  ws += 400128;
    unsigned short* hc16  = (unsigned short*)ws; ws += (size_t)NCHUNKS * HBINS * 2;  // 13.6 MB
    unsigned short* cum16 = (unsigned short*)ws; ws += (size_t)NCHUNKS * HBINS * 2;  // 13.6 MB
    int*    rank    = (int*)ws;    ws += (size_t)N_EDGES * sizeof(int);              // 6.4 MB
    int2*   edges   = (int2*)ws;   ws += (size_t)PEMAX * sizeof(int2);               // 25.6 MB
    __half* h       = (__half*)ws; ws += (size_t)N_NODES * NHID * sizeof(__half);
    __half* z       = (__half*)ws; ws += (size_t)N_NODES * NHID * sizeof(__half);
    __half* h2p     = (__half*)ws; ws += (size_t)N_NODES * 64 * sizeof(__half);

    hipMemsetAsync(deg_src, 0, (size_t)N_NODES * sizeof(int), stream);
    hipMemsetAsync(edges, 0, (size_t)PEMAX * sizeof(int2), stream);  // pad slots -> w=0

    dim3 hgrid(NGROUPS, NCHUNKS);   // 13 x 64 = 832 blocks each
    hist_src_kernel<<<hgrid, 256, 0, stream>>>(src, deg_src);
    hist_dst_kernel<<<hgrid, 256, 0, stream>>>(dst, hc16, rank);
    prep_kernel<<<(NTOT + 255) / 256, 256, 0, stream>>>(hc16, deg_src, cum16, pcnt, dinv);

    int nsb = (NTOT + SCAN_B - 1) / SCAN_B;  // 391 <= 512
    scan1_kernel<<<nsb, SCAN_B, 0, stream>>>(pcnt, partial, bsums);
    scan2_kernel<<<1, 512, 0, stream>>>(bsums, nsb);
    scan3_kernel<<<(NTOT + 255) / 256, 256, 0, stream>>>(partial, bsums, offs);

    fill4_kernel<<<(N_EDGES / 4 + 255) / 256, 256, 0, stream>>>(src, dst, dinv, offs, cum16, rank, edges);

    gemm1_kernel<<<(N_NODES + MROWS - 1) / MROWS, 256, 0, stream>>>(x, W1, b1, h);

    int nwblk = (N_NODES * 64 + 255) / 256;  // 25000 blocks, 4 waves each
    agg1_kernel<<<nwblk, 256, 0, stream>>>(offs, dinv, edges, h, z);
    gemm2_kernel<<<(N_NODES + MROWS - 1) / MROWS, 256, 0, stream>>>(z, W2, b2, h2p);
    agg2_kernel<<<nwblk, 256, 0, stream>>>(offs, dinv, edges, h2p, out);
}